// Round 10
// baseline (708.194 us; speedup 1.0000x reference)
//
#include <hip/hip_runtime.h>

#define N_WORDS 262144
#define N_TAGS  512
#define BDIM    768
#define MDIM    128
#define KS      32              // K per slice
#define NSL     (BDIM / KS)     // 24 slices
#define BW      64              // words per panel
#define NPAN    8               // panels per block (persistent)

typedef __attribute__((ext_vector_type(8))) short  bf16x8;
typedef __attribute__((ext_vector_type(4))) float  f32x4;

// async global->LDS, 16B per lane; dest base must be wave-uniform
#define GLOAD16(ldsdst, gsrc) __builtin_amdgcn_global_load_lds( \
    (const __attribute__((address_space(1))) unsigned int*)(gsrc), \
    (__attribute__((address_space(3))) unsigned int*)(ldsdst), 16, 0, 0)

// RNE fp32 -> bf16 (inputs finite)
__device__ inline unsigned bf16_1(float a) {
    union { float f; unsigned u; } ua; ua.f = a;
    unsigned x = ua.u;
    x += 0x7fffu + ((x >> 16) & 1u);
    return x >> 16;
}
// pack two fp32 -> (bf16(b)<<16)|bf16(a)
__device__ inline unsigned bf16_2(float a, float b) {
    union { float f; unsigned u; } ua, ub; ua.f = a; ub.f = b;
    unsigned x = ua.u, y = ub.u;
    x += 0x7fffu + ((x >> 16) & 1u);
    y += 0x7fffu + ((y >> 16) & 1u);
    return (x >> 16) | (y & 0xffff0000u);
}

// ---------------------------------------------------------------------------
// tags: Tm[t][m] = tags_embed[t].tags_W[m] + tags_b[m]  (fp32)
//   Tbf[t][m] = bf16(2*Tm)                  (k-contiguous rows)
//   cvec[t]   = 2*words_b.Tm_t - ||Tm_t||^2 (fp32)
// ---------------------------------------------------------------------------
__global__ __launch_bounds__(128) void tags_kernel(
    const float* __restrict__ tags_embed, const float* __restrict__ tags_W,
    const float* __restrict__ tags_b, const float* __restrict__ words_b,
    unsigned short* __restrict__ Tbf, float* __restrict__ cvec)
{
    __shared__ __align__(16) float sE[BDIM];
    __shared__ float red[128];
    const int t = blockIdx.x;
    const int m = threadIdx.x;

    for (int i = m; i < BDIM; i += 128) sE[i] = tags_embed[(size_t)t * BDIM + i];
    __syncthreads();

    float acc = tags_b[m];
    const float* Wr = tags_W + (size_t)m * BDIM;
    #pragma unroll 8
    for (int b = 0; b < BDIM; b += 4) {
        float4 w4 = *reinterpret_cast<const float4*>(Wr + b);
        float4 e4 = *reinterpret_cast<const float4*>(&sE[b]);
        acc += w4.x * e4.x + w4.y * e4.y + w4.z * e4.z + w4.w * e4.w;
    }
    Tbf[(size_t)t * MDIM + m] = (unsigned short)bf16_1(2.0f * acc);

    red[m] = acc * (2.0f * words_b[m] - acc);
    __syncthreads();
    for (int s = 64; s > 0; s >>= 1) {
        if (m < s) red[m] += red[m + s];
        __syncthreads();
    }
    if (m == 0) cvec[t] = red[0];
}

// ---------------------------------------------------------------------------
// wt: Wtbf[768][128] bf16 = transpose(words_W fp32 [128][768])
// ---------------------------------------------------------------------------
__global__ __launch_bounds__(256) void wt_kernel(
    const float* __restrict__ W, unsigned short* __restrict__ Wtbf)
{
    __shared__ float sT[32][33];
    const int bm = blockIdx.x & 3, bk = blockIdx.x >> 2;
    const int m0 = bm * 32, k0 = bk * 32;
    const int r = threadIdx.x >> 3, c = threadIdx.x & 7;

    f32x4 w4 = *reinterpret_cast<const f32x4*>(W + (size_t)(m0 + r) * BDIM + k0 + c * 4);
    sT[r][c * 4 + 0] = w4.x;  sT[r][c * 4 + 1] = w4.y;
    sT[r][c * 4 + 2] = w4.z;  sT[r][c * 4 + 3] = w4.w;
    __syncthreads();

    unsigned lo = bf16_2(sT[c * 4 + 0][r], sT[c * 4 + 1][r]);
    unsigned hi = bf16_2(sT[c * 4 + 2][r], sT[c * 4 + 3][r]);
    unsigned long long p = ((unsigned long long)hi << 32) | lo;
    *reinterpret_cast<unsigned long long*>(Wtbf + (size_t)(k0 + r) * MDIM + m0 + c * 4) = p;
}

// ---------------------------------------------------------------------------
// gt: G[tag][k] = sum_m Wt[k][m] * (2T)[tag][m]  -> stored SLICE-MAJOR:
//     GtSl[s][tag][k%32], s = k/32.
// ---------------------------------------------------------------------------
__global__ __launch_bounds__(64) void gt_kernel(
    const unsigned short* __restrict__ Wtbf, const unsigned short* __restrict__ Tbf,
    unsigned short* __restrict__ GtSl)
{
    const int kt = blockIdx.x % 48, tg = blockIdx.x / 48;
    const int k0 = kt * 16, t0 = tg * 64;
    const int n = threadIdx.x & 15, q = threadIdx.x >> 4;

    bf16x8 a[4];
    #pragma unroll
    for (int ks = 0; ks < 4; ++ks)
        a[ks] = *reinterpret_cast<const bf16x8*>(
            Wtbf + (size_t)(k0 + n) * MDIM + ks * 32 + q * 8);

    const int s2  = kt >> 1;
    const int off = (kt & 1) * 16 + 4 * q;     // k offset within slice

    #pragma unroll
    for (int tt = 0; tt < 4; ++tt) {
        f32x4 acc = (f32x4){0.f, 0.f, 0.f, 0.f};
        #pragma unroll
        for (int ks = 0; ks < 4; ++ks) {
            bf16x8 b = *reinterpret_cast<const bf16x8*>(
                Tbf + (size_t)(t0 + tt * 16 + n) * MDIM + ks * 32 + q * 8);
            acc = __builtin_amdgcn_mfma_f32_16x16x32_bf16(a[ks], b, acc, 0, 0, 0);
        }
        unsigned lo = bf16_2(acc.x, acc.y);
        unsigned hi = bf16_2(acc.z, acc.w);
        unsigned long long p = ((unsigned long long)hi << 32) | lo;
        *reinterpret_cast<unsigned long long*>(
            GtSl + (size_t)s2 * (N_TAGS * KS) + (size_t)(t0 + tt * 16 + n) * KS + off) = p;
    }
}

// ---------------------------------------------------------------------------
// main: PERSISTENT K-sliced LDS GEMM + fused softmax (round-7 core).
// 512 blocks (2/CU exactly) x 512 thr (8 waves); each block runs 8 panels of
// 64 words. Panel boundary is software-pipelined: next panel's slice-0 DMAs
// + E loads are issued in the epilogue (DMAs retired by the ds_write's
// implicit in-order vmcnt wait -- no manual count), and output stores stay
// in flight across the lgkmcnt-only panel barrier.
// ---------------------------------------------------------------------------
__global__ __launch_bounds__(512, 4) void main_kernel(
    const float* __restrict__ embed,                 // [N][768] fp32
    const unsigned short* __restrict__ GtSl,         // [24][512][32] bf16
    const float* __restrict__ cvec,                  // [512] fp32
    float* __restrict__ out_logp, float* __restrict__ out_p)
{
    __shared__ __align__(16) unsigned short sG[2 * N_TAGS * KS];  // 64 KB
    __shared__ __align__(16) unsigned short sE[2 * BW * KS];      // 8 KB
    __shared__ float sMx[8][BW];
    __shared__ float sSm[8][BW];

    const int tid  = threadIdx.x;
    const int lane = tid & 63;
    const int v    = tid >> 6;       // wave 0..7
    const int n    = lane & 15;
    const int q    = lane >> 4;
    const int we   = tid >> 3;       // staging word 0..63
    const int kp   = tid & 7;        // staging k-part
    const int w0base = blockIdx.x * (BW * NPAN);

    f32x4 eOld;

    // ---- first-panel prologue ----
    {
        const float* eSrc = embed + (size_t)(w0base + we) * BDIM + kp * 4;
        f32x4 e0 = *reinterpret_cast<const f32x4*>(eSrc);          // E(0)
        #pragma unroll
        for (int r = 0; r < 4; ++r)
            GLOAD16(sG + (r * 8 + v) * 512,
                    GtSl + (size_t)((r * 8 + v) * 64 + lane) * 8);
        eOld = *reinterpret_cast<const f32x4*>(eSrc + KS);         // E(1)
        unsigned lo = bf16_2(e0.x, e0.y), hi = bf16_2(e0.z, e0.w);
        *reinterpret_cast<unsigned long long*>(sE + we * KS + kp * 4) =
            ((unsigned long long)hi << 32) | lo;
        asm volatile("s_waitcnt vmcnt(1) lgkmcnt(0)\n\ts_barrier" ::: "memory");
    }

    #pragma unroll 1
    for (int p = 0; p < NPAN; ++p) {
        const int w0 = w0base + p * BW;
        const float* eSrc = embed + (size_t)(w0 + we) * BDIM + kp * 4;

        f32x4 acc[4][4];
        #pragma unroll
        for (int mt = 0; mt < 4; ++mt)
            #pragma unroll
            for (int wt = 0; wt < 4; ++wt)
                acc[mt][wt] = (f32x4){0.f, 0.f, 0.f, 0.f};

        // ---- K-loop (round-7 verbatim) ----
        int cur = 0;
        for (int s = 0; s < NSL; ++s) {
            const int nxt = cur ^ 1;

            if (s + 1 < NSL) {
                #pragma unroll
                for (int r = 0; r < 4; ++r)
                    GLOAD16(sG + nxt * (N_TAGS * KS) + (r * 8 + v) * 512,
                            GtSl + (size_t)(s + 1) * (N_TAGS * KS)
                                 + (size_t)((r * 8 + v) * 64 + lane) * 8);
            }
            f32x4 eNew;
            if (s + 2 < NSL)
                eNew = *reinterpret_cast<const f32x4*>(eSrc + (s + 2) * KS);

            if (s + 1 < NSL) {
                unsigned lo = bf16_2(eOld.x, eOld.y), hi = bf16_2(eOld.z, eOld.w);
                *reinterpret_cast<unsigned long long*>(
                    sE + nxt * (BW * KS) + we * KS + kp * 4) =
                    ((unsigned long long)hi << 32) | lo;
            }

            const unsigned short* sGc = sG + cur * (N_TAGS * KS);
            const unsigned short* sEc = sE + cur * (BW * KS);
            bf16x8 a[4], b[4];
            #pragma unroll
            for (int mt = 0; mt < 4; ++mt)
                a[mt] = *reinterpret_cast<const bf16x8*>(
                    sGc + (v * 64 + mt * 16 + n) * KS + q * 8);
            #pragma unroll
            for (int wt = 0; wt < 4; ++wt)
                b[wt] = *reinterpret_cast<const bf16x8*>(
                    sEc + (wt * 16 + n) * KS + q * 8);
            __builtin_amdgcn_s_setprio(1);
            #pragma unroll
            for (int mt = 0; mt < 4; ++mt)
                #pragma unroll
                for (int wt = 0; wt < 4; ++wt)
                    acc[mt][wt] = __builtin_amdgcn_mfma_f32_16x16x32_bf16(
                        a[mt], b[wt], acc[mt][wt], 0, 0, 0);
            __builtin_amdgcn_s_setprio(0);

            if (s + 2 < NSL) {
                asm volatile("s_waitcnt vmcnt(1) lgkmcnt(0)\n\ts_barrier" ::: "memory");
            } else if (s + 1 < NSL) {
                asm volatile("s_waitcnt vmcnt(0) lgkmcnt(0)\n\ts_barrier" ::: "memory");
            }
            eOld = eNew;
            cur = nxt;
        }

        // ---- + cvec ----
        #pragma unroll
        for (int mt = 0; mt < 4; ++mt) {
            f32x4 c4 = *reinterpret_cast<const f32x4*>(cvec + v * 64 + mt * 16 + 4 * q);
            #pragma unroll
            for (int wt = 0; wt < 4; ++wt) acc[mt][wt] += c4;
        }

        // ---- per-word partial softmax ----
        float mx[4], sm[4];
        #pragma unroll
        for (int wt = 0; wt < 4; ++wt) {
            float m = -3.0e38f;
            #pragma unroll
            for (int mt = 0; mt < 4; ++mt)
                m = fmaxf(m, fmaxf(fmaxf(acc[mt][wt].x, acc[mt][wt].y),
                                   fmaxf(acc[mt][wt].z, acc[mt][wt].w)));
            m = fmaxf(m, __shfl_xor(m, 16, 64));
            m = fmaxf(m, __shfl_xor(m, 32, 64));
            mx[wt] = m;
            float s = 0.f;
            #pragma unroll
            for (int mt = 0; mt < 4; ++mt)
                s += __expf(acc[mt][wt].x - m) + __expf(acc[mt][wt].y - m)
                   + __expf(acc[mt][wt].z - m) + __expf(acc[mt][wt].w - m);
            s += __shfl_xor(s, 16, 64);
            s += __shfl_xor(s, 32, 64);
            sm[wt] = s;
        }
        if (q == 0) {
            #pragma unroll
            for (int wt = 0; wt < 4; ++wt) {
                sMx[v][wt * 16 + n] = mx[wt];
                sSm[v][wt * 16 + n] = sm[wt];
            }
        }
        __syncthreads();   // all waves done with K-loop; sG[0]/sE[0] idle

        // ---- overlapped next-panel prologue: DMAs FIRST, then E loads ----
        f32x4 e0n;
        if (p + 1 < NPAN) {
            #pragma unroll
            for (int r = 0; r < 4; ++r)
                GLOAD16(sG + (r * 8 + v) * 512,
                        GtSl + (size_t)((r * 8 + v) * 64 + lane) * 8);
            const float* eSrcN = eSrc + BW * BDIM;
            e0n  = *reinterpret_cast<const f32x4*>(eSrcN);
            eOld = *reinterpret_cast<const f32x4*>(eSrcN + KS);
        }

        // ---- cross-wave combine + stores (stores stay in flight) ----
        #pragma unroll
        for (int wt = 0; wt < 4; ++wt) {
            const int wd = wt * 16 + n;
            float M = sMx[0][wd];
            #pragma unroll
            for (int u = 1; u < 8; ++u) M = fmaxf(M, sMx[u][wd]);
            float S = 0.f;
            #pragma unroll
            for (int u = 0; u < 8; ++u) S += sSm[u][wd] * __expf(sMx[u][wd] - M);
            const float neg = M + __logf(S);

            const size_t row = (size_t)(w0 + wd) * N_TAGS + v * 64 + 4 * q;
            #pragma unroll
            for (int mt = 0; mt < 4; ++mt) {
                f32x4 lp, pp;
                lp.x = acc[mt][wt].x - neg;  pp.x = __expf(lp.x);
                lp.y = acc[mt][wt].y - neg;  pp.y = __expf(lp.y);
                lp.z = acc[mt][wt].z - neg;  pp.z = __expf(lp.z);
                lp.w = acc[mt][wt].w - neg;  pp.w = __expf(lp.w);
                *reinterpret_cast<f32x4*>(out_logp + row + mt * 16) = lp;
                *reinterpret_cast<f32x4*>(out_p    + row + mt * 16) = pp;
            }
        }

        if (p + 1 < NPAN) {
            // ds_write E(0): implicit in-order vmcnt wait retires [DMAx4, e0n]
            // (both older than the stores, which keep flying).
            unsigned lo = bf16_2(e0n.x, e0n.y), hi = bf16_2(e0n.z, e0n.w);
            *reinterpret_cast<unsigned long long*>(sE + we * KS + kp * 4) =
                ((unsigned long long)hi << 32) | lo;
            asm volatile("s_waitcnt lgkmcnt(0)\n\ts_barrier" ::: "memory");
        }
    }
}

extern "C" void kernel_launch(void* const* d_in, const int* in_sizes, int n_in,
                              void* d_out, int out_size, void* d_ws, size_t ws_size,
                              hipStream_t stream) {
    const float* tags_embed  = (const float*)d_in[0];
    const float* words_embed = (const float*)d_in[1];
    const float* tags_W      = (const float*)d_in[2];
    const float* tags_b      = (const float*)d_in[3];
    const float* words_W     = (const float*)d_in[4];
    const float* words_b     = (const float*)d_in[5];

    float* out_logp = (float*)d_out;
    float* out_p    = out_logp + (size_t)N_WORDS * N_TAGS;

    // ws: Tbf [512][128] bf16 | cvec [512] f32 | Wtbf [768][128] bf16 |
    //     GtSl [24][512][32] bf16
    unsigned short* Tbf  = (unsigned short*)d_ws;
    float*          cvec = (float*)(Tbf + (size_t)N_TAGS * MDIM);
    unsigned short* Wtbf = (unsigned short*)(cvec + N_TAGS);
    unsigned short* GtSl = Wtbf + (size_t)BDIM * MDIM;

    tags_kernel<<<N_TAGS, 128, 0, stream>>>(tags_embed, tags_W, tags_b, words_b, Tbf, cvec);
    wt_kernel<<<96, 256, 0, stream>>>(words_W, Wtbf);
    gt_kernel<<<384, 64, 0, stream>>>(Wtbf, Tbf, GtSl);
    main_kernel<<<N_WORDS / (BW * NPAN), 512, 0, stream>>>(
        words_embed, GtSl, cvec, out_logp, out_p);
}

// Round 11
// 615.359 us; speedup vs baseline: 1.1509x; 1.1509x over previous
//
#include <hip/hip_runtime.h>

#define N_WORDS 262144
#define N_TAGS  512
#define BDIM    768
#define MDIM    128
#define KS      32              // K per slice
#define NSL     (BDIM / KS)     // 24 slices
#define BW      64              // words per block

typedef __attribute__((ext_vector_type(8))) short  bf16x8;
typedef __attribute__((ext_vector_type(4))) float  f32x4;

// RNE fp32 -> bf16 (inputs finite)
__device__ inline unsigned bf16_1(float a) {
    union { float f; unsigned u; } ua; ua.f = a;
    unsigned x = ua.u;
    x += 0x7fffu + ((x >> 16) & 1u);
    return x >> 16;
}
// pack two fp32 -> (bf16(b)<<16)|bf16(a)
__device__ inline unsigned bf16_2(float a, float b) {
    union { float f; unsigned u; } ua, ub; ua.f = a; ub.f = b;
    unsigned x = ua.u, y = ub.u;
    x += 0x7fffu + ((x >> 16) & 1u);
    y += 0x7fffu + ((y >> 16) & 1u);
    return (x >> 16) | (y & 0xffff0000u);
}

// ---------------------------------------------------------------------------
// tags: Tm[t][m] = tags_embed[t].tags_W[m] + tags_b[m]  (fp32)
//   Tbf[t][m] = bf16(2*Tm)                  (k-contiguous rows)
//   cvec[t]   = 2*words_b.Tm_t - ||Tm_t||^2 (fp32)
// ---------------------------------------------------------------------------
__global__ __launch_bounds__(128) void tags_kernel(
    const float* __restrict__ tags_embed, const float* __restrict__ tags_W,
    const float* __restrict__ tags_b, const float* __restrict__ words_b,
    unsigned short* __restrict__ Tbf, float* __restrict__ cvec)
{
    __shared__ __align__(16) float sE[BDIM];
    __shared__ float red[128];
    const int t = blockIdx.x;
    const int m = threadIdx.x;

    for (int i = m; i < BDIM; i += 128) sE[i] = tags_embed[(size_t)t * BDIM + i];
    __syncthreads();

    float acc = tags_b[m];
    const float* Wr = tags_W + (size_t)m * BDIM;
    #pragma unroll 8
    for (int b = 0; b < BDIM; b += 4) {
        float4 w4 = *reinterpret_cast<const float4*>(Wr + b);
        float4 e4 = *reinterpret_cast<const float4*>(&sE[b]);
        acc += w4.x * e4.x + w4.y * e4.y + w4.z * e4.z + w4.w * e4.w;
    }
    Tbf[(size_t)t * MDIM + m] = (unsigned short)bf16_1(2.0f * acc);

    red[m] = acc * (2.0f * words_b[m] - acc);
    __syncthreads();
    for (int s = 64; s > 0; s >>= 1) {
        if (m < s) red[m] += red[m + s];
        __syncthreads();
    }
    if (m == 0) cvec[t] = red[0];
}

// ---------------------------------------------------------------------------
// wt: Wtbf[768][128] bf16 = transpose(words_W fp32 [128][768])
// ---------------------------------------------------------------------------
__global__ __launch_bounds__(256) void wt_kernel(
    const float* __restrict__ W, unsigned short* __restrict__ Wtbf)
{
    __shared__ float sT[32][33];
    const int bm = blockIdx.x & 3, bk = blockIdx.x >> 2;
    const int m0 = bm * 32, k0 = bk * 32;
    const int r = threadIdx.x >> 3, c = threadIdx.x & 7;

    f32x4 w4 = *reinterpret_cast<const f32x4*>(W + (size_t)(m0 + r) * BDIM + k0 + c * 4);
    sT[r][c * 4 + 0] = w4.x;  sT[r][c * 4 + 1] = w4.y;
    sT[r][c * 4 + 2] = w4.z;  sT[r][c * 4 + 3] = w4.w;
    __syncthreads();

    unsigned lo = bf16_2(sT[c * 4 + 0][r], sT[c * 4 + 1][r]);
    unsigned hi = bf16_2(sT[c * 4 + 2][r], sT[c * 4 + 3][r]);
    unsigned long long p = ((unsigned long long)hi << 32) | lo;
    *reinterpret_cast<unsigned long long*>(Wtbf + (size_t)(k0 + r) * MDIM + m0 + c * 4) = p;
}

// ---------------------------------------------------------------------------
// gt: G[tag][k] = sum_m Wt[k][m] * (2T)[tag][m]  -> stored SLICE-MAJOR:
//     GtSl[s][tag][k%32], s = k/32.
// ---------------------------------------------------------------------------
__global__ __launch_bounds__(64) void gt_kernel(
    const unsigned short* __restrict__ Wtbf, const unsigned short* __restrict__ Tbf,
    unsigned short* __restrict__ GtSl)
{
    const int kt = blockIdx.x % 48, tg = blockIdx.x / 48;
    const int k0 = kt * 16, t0 = tg * 64;
    const int n = threadIdx.x & 15, q = threadIdx.x >> 4;

    bf16x8 a[4];
    #pragma unroll
    for (int ks = 0; ks < 4; ++ks)
        a[ks] = *reinterpret_cast<const bf16x8*>(
            Wtbf + (size_t)(k0 + n) * MDIM + ks * 32 + q * 8);

    const int s2  = kt >> 1;
    const int off = (kt & 1) * 16 + 4 * q;     // k offset within slice

    #pragma unroll
    for (int tt = 0; tt < 4; ++tt) {
        f32x4 acc = (f32x4){0.f, 0.f, 0.f, 0.f};
        #pragma unroll
        for (int ks = 0; ks < 4; ++ks) {
            bf16x8 b = *reinterpret_cast<const bf16x8*>(
                Tbf + (size_t)(t0 + tt * 16 + n) * MDIM + ks * 32 + q * 8);
            acc = __builtin_amdgcn_mfma_f32_16x16x32_bf16(a[ks], b, acc, 0, 0, 0);
        }
        unsigned lo = bf16_2(acc.x, acc.y);
        unsigned hi = bf16_2(acc.z, acc.w);
        unsigned long long p = ((unsigned long long)hi << 32) | lo;
        *reinterpret_cast<unsigned long long*>(
            GtSl + (size_t)s2 * (N_TAGS * KS) + (size_t)(t0 + tt * 16 + n) * KS + off) = p;
    }
}

// ---------------------------------------------------------------------------
// main: VMCNT-DECOUPLED K-sliced GEMM + fused softmax.
// 4096 blocks x 512 thr (8 waves). Block = 64 words x 512 tags.
// A-frags (Gt, disjoint per wave): direct L2 register loads, prefetched
//   1 slice ahead -- NO LDS staging, NO vmcnt at barriers. The compiler
//   emits exact per-consumer vmcnt; loads fly across barriers.
// E: depth-2 reg pipeline through a tiny 8 KB LDS dbuf (as r7).
// Barrier: s_waitcnt lgkmcnt(0); s_barrier  (only E ds ops).
// Reg budget: 64 AGPR acc + aC/aN 32 + E 8 + addr ~20 -> 4 waves/SIMD.
// ---------------------------------------------------------------------------
__global__ __launch_bounds__(512, 4) void main_kernel(
    const float* __restrict__ embed,                 // [N][768] fp32
    const unsigned short* __restrict__ GtSl,         // [24][512][32] bf16
    const float* __restrict__ cvec,                  // [512] fp32
    float* __restrict__ out_logp, float* __restrict__ out_p)
{
    __shared__ __align__(16) unsigned short sE[2 * BW * KS];      // 8 KB
    __shared__ float sMx[8][BW];
    __shared__ float sSm[8][BW];

    const int tid  = threadIdx.x;
    const int lane = tid & 63;
    const int v    = tid >> 6;       // wave 0..7 -> tags v*64..+63
    const int n    = lane & 15;
    const int q    = lane >> 4;
    const int we   = tid >> 3;       // staging word 0..63
    const int kp   = tid & 7;        // staging k-part
    const int w0   = blockIdx.x * BW;

    const float* eSrc = embed + (size_t)(w0 + we) * BDIM + kp * 4;
    const unsigned short* Ab = GtSl + (size_t)(v * 64 + n) * KS + q * 8;

    // ---- prologue: E(0)->LDS, E(1) in flight, A(0) in flight ----
    f32x4 eOld;
    bf16x8 aC[4], aN[4];
    {
        f32x4 e0 = *reinterpret_cast<const f32x4*>(eSrc);          // E(0)
        #pragma unroll
        for (int mt = 0; mt < 4; ++mt)
            aC[mt] = *reinterpret_cast<const bf16x8*>(Ab + mt * (16 * KS));
        eOld = *reinterpret_cast<const f32x4*>(eSrc + KS);         // E(1)
        unsigned lo = bf16_2(e0.x, e0.y), hi = bf16_2(e0.z, e0.w); // waits e0 only
        *reinterpret_cast<unsigned long long*>(sE + we * KS + kp * 4) =
            ((unsigned long long)hi << 32) | lo;
        asm volatile("s_waitcnt lgkmcnt(0)\n\ts_barrier" ::: "memory");
    }

    f32x4 acc[4][4];
    #pragma unroll
    for (int mt = 0; mt < 4; ++mt)
        #pragma unroll
        for (int wt = 0; wt < 4; ++wt)
            acc[mt][wt] = (f32x4){0.f, 0.f, 0.f, 0.f};

    int cur = 0;
    for (int s = 0; s < NSL; ++s) {
        const int nxt = cur ^ 1;

        f32x4 eNew;
        if (s + 1 < NSL) {
            // A-frag prefetch slice s+1 (pure register, flies across barrier)
            #pragma unroll
            for (int mt = 0; mt < 4; ++mt)
                aN[mt] = *reinterpret_cast<const bf16x8*>(
                    Ab + (size_t)(s + 1) * (N_TAGS * KS) + mt * (16 * KS));
            // E-load for slice s+2
            if (s + 2 < NSL)
                eNew = *reinterpret_cast<const f32x4*>(eSrc + (s + 2) * KS);
            // ds_write E(s+1) (loaded 2 slices ago; compiler waits only it)
            unsigned lo = bf16_2(eOld.x, eOld.y), hi = bf16_2(eOld.z, eOld.w);
            *reinterpret_cast<unsigned long long*>(
                sE + nxt * (BW * KS) + we * KS + kp * 4) =
                ((unsigned long long)hi << 32) | lo;
        }

        // compute slice s
        const unsigned short* sEc = sE + cur * (BW * KS);
        bf16x8 b[4];
        #pragma unroll
        for (int wt = 0; wt < 4; ++wt)
            b[wt] = *reinterpret_cast<const bf16x8*>(
                sEc + (wt * 16 + n) * KS + q * 8);
        __builtin_amdgcn_s_setprio(1);
        #pragma unroll
        for (int mt = 0; mt < 4; ++mt)
            #pragma unroll
            for (int wt = 0; wt < 4; ++wt)
                acc[mt][wt] = __builtin_amdgcn_mfma_f32_16x16x32_bf16(
                    aC[mt], b[wt], acc[mt][wt], 0, 0, 0);
        __builtin_amdgcn_s_setprio(0);

        if (s + 1 < NSL) {
            // lgkm-only barrier: E writes visible; global loads keep flying
            asm volatile("s_waitcnt lgkmcnt(0)\n\ts_barrier" ::: "memory");
            #pragma unroll
            for (int mt = 0; mt < 4; ++mt) aC[mt] = aN[mt];
            eOld = eNew;
        }
        cur = nxt;
    }

    // ---- + cvec: tag = v*64 + mt*16 + 4q + r ----
    #pragma unroll
    for (int mt = 0; mt < 4; ++mt) {
        f32x4 c4 = *reinterpret_cast<const f32x4*>(cvec + v * 64 + mt * 16 + 4 * q);
        #pragma unroll
        for (int wt = 0; wt < 4; ++wt) acc[mt][wt] += c4;
    }

    // ---- per-word partial softmax (wave: 64 tags x 64 words) ----
    float mx[4], sm[4];
    #pragma unroll
    for (int wt = 0; wt < 4; ++wt) {
        float m = -3.0e38f;
        #pragma unroll
        for (int mt = 0; mt < 4; ++mt)
            m = fmaxf(m, fmaxf(fmaxf(acc[mt][wt].x, acc[mt][wt].y),
                               fmaxf(acc[mt][wt].z, acc[mt][wt].w)));
        m = fmaxf(m, __shfl_xor(m, 16, 64));
        m = fmaxf(m, __shfl_xor(m, 32, 64));
        mx[wt] = m;
        float s = 0.f;
        #pragma unroll
        for (int mt = 0; mt < 4; ++mt)
            s += __expf(acc[mt][wt].x - m) + __expf(acc[mt][wt].y - m)
               + __expf(acc[mt][wt].z - m) + __expf(acc[mt][wt].w - m);
        s += __shfl_xor(s, 16, 64);
        s += __shfl_xor(s, 32, 64);
        sm[wt] = s;
    }
    if (q == 0) {
        #pragma unroll
        for (int wt = 0; wt < 4; ++wt) {
            sMx[v][wt * 16 + n] = mx[wt];
            sSm[v][wt * 16 + n] = sm[wt];
        }
    }
    __syncthreads();

    // ---- cross-wave combine + epilogue stores ----
    #pragma unroll
    for (int wt = 0; wt < 4; ++wt) {
        const int wd = wt * 16 + n;
        float M = sMx[0][wd];
        #pragma unroll
        for (int u = 1; u < 8; ++u) M = fmaxf(M, sMx[u][wd]);
        float S = 0.f;
        #pragma unroll
        for (int u = 0; u < 8; ++u) S += sSm[u][wd] * __expf(sMx[u][wd] - M);
        const float neg = M + __logf(S);

        const size_t row = (size_t)(w0 + wd) * N_TAGS + v * 64 + 4 * q;
        #pragma unroll
        for (int mt = 0; mt < 4; ++mt) {
            f32x4 lp, pp;
            lp.x = acc[mt][wt].x - neg;  pp.x = __expf(lp.x);
            lp.y = acc[mt][wt].y - neg;  pp.y = __expf(lp.y);
            lp.z = acc[mt][wt].z - neg;  pp.z = __expf(lp.z);
            lp.w = acc[mt][wt].w - neg;  pp.w = __expf(lp.w);
            *reinterpret_cast<f32x4*>(out_logp + row + mt * 16) = lp;
            *reinterpret_cast<f32x4*>(out_p    + row + mt * 16) = pp;
        }
    }
}

extern "C" void kernel_launch(void* const* d_in, const int* in_sizes, int n_in,
                              void* d_out, int out_size, void* d_ws, size_t ws_size,
                              hipStream_t stream) {
    const float* tags_embed  = (const float*)d_in[0];
    const float* words_embed = (const float*)d_in[1];
    const float* tags_W      = (const float*)d_in[2];
    const float* tags_b      = (const float*)d_in[3];
    const float* words_W     = (const float*)d_in[4];
    const float* words_b     = (const float*)d_in[5];

    float* out_logp = (float*)d_out;
    float* out_p    = out_logp + (size_t)N_WORDS * N_TAGS;

    // ws: Tbf [512][128] bf16 | cvec [512] f32 | Wtbf [768][128] bf16 |
    //     GtSl [24][512][32] bf16
    unsigned short* Tbf  = (unsigned short*)d_ws;
    float*          cvec = (float*)(Tbf + (size_t)N_TAGS * MDIM);
    unsigned short* Wtbf = (unsigned short*)(cvec + N_TAGS);
    unsigned short* GtSl = Wtbf + (size_t)BDIM * MDIM;

    tags_kernel<<<N_TAGS, 128, 0, stream>>>(tags_embed, tags_W, tags_b, words_b, Tbf, cvec);
    wt_kernel<<<96, 256, 0, stream>>>(words_W, Wtbf);
    gt_kernel<<<384, 64, 0, stream>>>(Wtbf, Tbf, GtSl);
    main_kernel<<<N_WORDS / BW, 512, 0, stream>>>(
        words_embed, GtSl, cvec, out_logp, out_p);
}